// Round 2
// baseline (1042.197 us; speedup 1.0000x reference)
//
#include <hip/hip_runtime.h>

// ---------------------------------------------------------------------------
// LlamaAttention forward: B=1, S=2048, HID=4096, NH=32, NKV=8, HD=128, GQA x4
// Inputs fp32 (per reference dtypes), output fp32. Internally: bf16 MFMA with
// fp32 accumulation. Pipeline: cast hs -> transpose+cast weights ->
// QKV GEMMs -> RoPE -> V transpose -> flash attention -> O GEMM (fp32 out).
// ---------------------------------------------------------------------------

typedef __bf16 bf16_t;
typedef bf16_t bf16x8_t __attribute__((ext_vector_type(8)));
typedef float f32x4_t __attribute__((ext_vector_type(4)));

#define S_LEN 2048
#define HID 4096
#define NH 32
#define NKV 8
#define HD 128
#define KV_DIM (NKV * HD)   // 1024
#define SCALE 0.08838834764831845f  // 1/sqrt(128)

// -------- persistent device scratch (avoids ws_size assumptions) -----------
__device__ __align__(16) bf16_t g_hsb[(size_t)S_LEN * HID];       // hs in bf16
__device__ __align__(16) bf16_t g_wqT[(size_t)HID * HID];         // [n][k] bf16
__device__ __align__(16) bf16_t g_wkT[(size_t)KV_DIM * HID];
__device__ __align__(16) bf16_t g_wvT[(size_t)KV_DIM * HID];
__device__ __align__(16) bf16_t g_woT[(size_t)HID * HID];
__device__ __align__(16) bf16_t g_q [(size_t)S_LEN * HID];        // post-RoPE
__device__ __align__(16) bf16_t g_k [(size_t)S_LEN * KV_DIM];     // post-RoPE
__device__ __align__(16) bf16_t g_v [(size_t)S_LEN * KV_DIM];
__device__ __align__(16) bf16_t g_vT[(size_t)NKV * HD * S_LEN];   // [kvh][d][s]
__device__ __align__(16) bf16_t g_ao[(size_t)S_LEN * HID];        // attn out

// ---------------------------------------------------------------------------
// fp32 -> bf16 elementwise cast (hidden_states), 8 elems/thread.
// ---------------------------------------------------------------------------
__global__ __launch_bounds__(256) void cast_f32_bf16(
    const float* __restrict__ in, bf16_t* __restrict__ out)
{
  size_t i = ((size_t)blockIdx.x * 256 + threadIdx.x) * 8;
  float4 a = *(const float4*)(in + i);
  float4 b = *(const float4*)(in + i + 4);
  bf16x8_t r;
  r[0] = (bf16_t)a.x; r[1] = (bf16_t)a.y; r[2] = (bf16_t)a.z; r[3] = (bf16_t)a.w;
  r[4] = (bf16_t)b.x; r[5] = (bf16_t)b.y; r[6] = (bf16_t)b.z; r[7] = (bf16_t)b.w;
  *(bf16x8_t*)(out + i) = r;
}

// ---------------------------------------------------------------------------
// Transpose + cast: in fp32 [R][C] (row stride is), out bf16 [C][R] (stride os)
// 64x64 LDS tile.
// ---------------------------------------------------------------------------
__global__ __launch_bounds__(256) void transpose_f32_bf16(
    const float* __restrict__ in, bf16_t* __restrict__ out, int is, int os)
{
  __shared__ __align__(16) bf16_t T[64 * 72];
  int r0 = blockIdx.x * 64, c0 = blockIdx.y * 64;
  int t = threadIdx.x;
#pragma unroll
  for (int it = 0; it < 2; ++it) {
    int idx = t + it * 256;            // 0..511
    int r = idx >> 3, c8 = (idx & 7) * 8;
    const float* p = in + (size_t)(r0 + r) * is + c0 + c8;
    float4 a = *(const float4*)p;
    float4 b = *(const float4*)(p + 4);
    bf16x8_t x;
    x[0] = (bf16_t)a.x; x[1] = (bf16_t)a.y; x[2] = (bf16_t)a.z; x[3] = (bf16_t)a.w;
    x[4] = (bf16_t)b.x; x[5] = (bf16_t)b.y; x[6] = (bf16_t)b.z; x[7] = (bf16_t)b.w;
    *(bf16x8_t*)(T + r * 72 + c8) = x;
  }
  __syncthreads();
#pragma unroll
  for (int it = 0; it < 2; ++it) {
    int idx = t + it * 256;
    int c = idx >> 3, r8 = (idx & 7) * 8;
    bf16x8_t x;
#pragma unroll
    for (int i = 0; i < 8; ++i) x[i] = T[(r8 + i) * 72 + c];
    *(bf16x8_t*)(out + (size_t)(c0 + c) * os + r0 + r8) = x;
  }
}

// ---------------------------------------------------------------------------
// bf16 transpose (batched) for V: out[z][c][r] = in[r][z*in_b + c].
// ---------------------------------------------------------------------------
__global__ __launch_bounds__(256) void transpose_bf16(
    const bf16_t* __restrict__ in, bf16_t* __restrict__ out,
    int is, int os, int in_b, int out_b)
{
  __shared__ __align__(16) bf16_t T[64 * 72];
  const bf16_t* inp = in + (size_t)blockIdx.z * in_b;
  bf16_t* outp = out + (size_t)blockIdx.z * out_b;
  int r0 = blockIdx.x * 64, c0 = blockIdx.y * 64;
  int t = threadIdx.x;
#pragma unroll
  for (int it = 0; it < 2; ++it) {
    int idx = t + it * 256;
    int r = idx >> 3, c8 = (idx & 7) * 8;
    *(bf16x8_t*)(T + r * 72 + c8) =
        *(const bf16x8_t*)(inp + (size_t)(r0 + r) * is + c0 + c8);
  }
  __syncthreads();
#pragma unroll
  for (int it = 0; it < 2; ++it) {
    int idx = t + it * 256;
    int c = idx >> 3, r8 = (idx & 7) * 8;
    bf16x8_t x;
#pragma unroll
    for (int i = 0; i < 8; ++i) x[i] = T[(r8 + i) * 72 + c];
    *(bf16x8_t*)(outp + (size_t)(c0 + c) * os + r0 + r8) = x;
  }
}

// ---------------------------------------------------------------------------
// GEMM: C[M,N] = A[M,K] @ Bt[N,K]^T, bf16 in, fp32 acc, CT out.
// 64x64 block tile, BK=32, 4 waves each computing 16 rows x 64 cols.
// MFMA 16x16x32 layouts (HW-verified): A[m=lane&15][k=(lane>>4)*8+j],
// B[k=(lane>>4)*8+j][n=lane&15], D row=(lane>>4)*4+r, col=lane&15.
// ---------------------------------------------------------------------------
template <typename CT>
__global__ __launch_bounds__(256) void gemm_bt(
    const bf16_t* __restrict__ A, const bf16_t* __restrict__ Bt,
    CT* __restrict__ C, int K, int N)
{
  __shared__ __align__(16) bf16_t As[64 * 40];   // pad 32->40
  __shared__ __align__(16) bf16_t Bs[64 * 40];
  int t = threadIdx.x;
  int wave = t >> 6, lane = t & 63, ln = lane & 15, lq = lane >> 4;
  int m0 = blockIdx.x * 64, n0 = blockIdx.y * 64;
  int sr = t >> 2, sc = (t & 3) * 8;
  f32x4_t acc[4] = {};
  const bf16_t* Arow = A + (size_t)(m0 + sr) * K + sc;
  const bf16_t* Brow = Bt + (size_t)(n0 + sr) * K + sc;
  for (int k0 = 0; k0 < K; k0 += 32) {
    __syncthreads();
    *(bf16x8_t*)(As + sr * 40 + sc) = *(const bf16x8_t*)(Arow + k0);
    *(bf16x8_t*)(Bs + sr * 40 + sc) = *(const bf16x8_t*)(Brow + k0);
    __syncthreads();
    bf16x8_t af = *(const bf16x8_t*)(As + (wave * 16 + ln) * 40 + lq * 8);
#pragma unroll
    for (int c = 0; c < 4; ++c) {
      bf16x8_t bfr = *(const bf16x8_t*)(Bs + (c * 16 + ln) * 40 + lq * 8);
      acc[c] = __builtin_amdgcn_mfma_f32_16x16x32_bf16(af, bfr, acc[c], 0, 0, 0);
    }
  }
#pragma unroll
  for (int c = 0; c < 4; ++c)
#pragma unroll
    for (int r = 0; r < 4; ++r)
      C[(size_t)(m0 + wave * 16 + lq * 4 + r) * N + n0 + c * 16 + ln] =
          (CT)acc[c][r];
}

// ---------------------------------------------------------------------------
// RoPE in-place on q and k; cos/sin fp32 [S][128], second half dup of first.
// ---------------------------------------------------------------------------
__global__ __launch_bounds__(256) void rope_kernel(
    bf16_t* __restrict__ q, bf16_t* __restrict__ k,
    const float* __restrict__ cs, const float* __restrict__ sn)
{
  int idx = blockIdx.x * 256 + threadIdx.x;   // S * (NH+NKV) * 64 exact
  int d = idx & 63;
  int h = (idx >> 6) % (NH + NKV);
  int s = idx / (64 * (NH + NKV));
  float c = cs[s * HD + d];
  float si = sn[s * HD + d];
  bf16_t* base = (h < NH) ? (q + (size_t)s * HID + h * HD)
                          : (k + (size_t)s * KV_DIM + (h - NH) * HD);
  float x1 = (float)base[d], x2 = (float)base[d + 64];
  base[d]      = (bf16_t)(x1 * c - x2 * si);
  base[d + 64] = (bf16_t)(x2 * c + x1 * si);
}

// ---------------------------------------------------------------------------
// Flash attention, causal, GQA (head h -> kv head h>>2).
// 256 thr = 4 waves; 64 q-rows/block (16/wave); K-tiles of 32; online softmax.
// ---------------------------------------------------------------------------
__global__ __launch_bounds__(256) void attn_kernel(
    const bf16_t* __restrict__ Q, const bf16_t* __restrict__ Kb,
    const bf16_t* __restrict__ VT, bf16_t* __restrict__ O)
{
  __shared__ __align__(16) bf16_t Ks[32 * 136];   // [kpos][dim], pad 128->136
  __shared__ __align__(16) bf16_t Vs[128 * 40];   // [dim][kpos], pad 32->40
  __shared__ __align__(16) bf16_t Ps[4 * 16 * 40];// per-wave P
  int t = threadIdx.x, wave = t >> 6, lane = t & 63;
  int ln = lane & 15, lq = lane >> 4;
  int head = blockIdx.y, kvh = head >> 2;
  int q0 = blockIdx.x * 64;
  int qr = q0 + wave * 16 + ln;

  bf16x8_t qf[4];
#pragma unroll
  for (int kk = 0; kk < 4; ++kk)
    qf[kk] = *(const bf16x8_t*)(Q + (size_t)qr * HID + head * HD + kk * 32 + lq * 8);

  f32x4_t oa[8] = {};
  float m_r[4] = {-1e30f, -1e30f, -1e30f, -1e30f};
  float l_r[4] = {0.f, 0.f, 0.f, 0.f};
  int ktend = (q0 + 63) >> 5;
  int srow = t >> 4, scol = (t & 15) * 8;

  for (int kt = 0; kt <= ktend; ++kt) {
    int kb = kt * 32;
    __syncthreads();
#pragma unroll
    for (int it = 0; it < 2; ++it) {
      int kp = srow + it * 16;
      *(bf16x8_t*)(Ks + kp * 136 + scol) =
          *(const bf16x8_t*)(Kb + (size_t)(kb + kp) * KV_DIM + kvh * HD + scol);
    }
#pragma unroll
    for (int it = 0; it < 2; ++it) {
      int idx = t + it * 256;
      int dim = idx >> 2, kc = (idx & 3) * 8;
      *(bf16x8_t*)(Vs + dim * 40 + kc) =
          *(const bf16x8_t*)(VT + ((size_t)kvh * HD + dim) * S_LEN + kb + kc);
    }
    __syncthreads();

    f32x4_t s0 = {}, s1 = {};
#pragma unroll
    for (int kk = 0; kk < 4; ++kk) {
      bf16x8_t b0 = *(const bf16x8_t*)(Ks + ln * 136 + kk * 32 + lq * 8);
      bf16x8_t b1 = *(const bf16x8_t*)(Ks + (16 + ln) * 136 + kk * 32 + lq * 8);
      s0 = __builtin_amdgcn_mfma_f32_16x16x32_bf16(qf[kk], b0, s0, 0, 0, 0);
      s1 = __builtin_amdgcn_mfma_f32_16x16x32_bf16(qf[kk], b1, s1, 0, 0, 0);
    }

    float sc0[4], sc1[4];
#pragma unroll
    for (int r = 0; r < 4; ++r) {
      int qg = q0 + wave * 16 + lq * 4 + r;
      sc0[r] = (kb + ln <= qg) ? s0[r] * SCALE : -1e30f;
      sc1[r] = (kb + 16 + ln <= qg) ? s1[r] * SCALE : -1e30f;
    }
    float mx[4];
#pragma unroll
    for (int r = 0; r < 4; ++r) mx[r] = fmaxf(sc0[r], sc1[r]);
#pragma unroll
    for (int off = 8; off >= 1; off >>= 1)
#pragma unroll
      for (int r = 0; r < 4; ++r) mx[r] = fmaxf(mx[r], __shfl_xor(mx[r], off, 64));

    float al[4], p0[4], p1[4], rs[4];
#pragma unroll
    for (int r = 0; r < 4; ++r) {
      float mn = fmaxf(m_r[r], mx[r]);
      al[r] = __expf(m_r[r] - mn);
      m_r[r] = mn;
      p0[r] = __expf(sc0[r] - mn);
      p1[r] = __expf(sc1[r] - mn);
      rs[r] = p0[r] + p1[r];
    }
#pragma unroll
    for (int off = 8; off >= 1; off >>= 1)
#pragma unroll
      for (int r = 0; r < 4; ++r) rs[r] += __shfl_xor(rs[r], off, 64);
#pragma unroll
    for (int r = 0; r < 4; ++r) l_r[r] = l_r[r] * al[r] + rs[r];
#pragma unroll
    for (int c = 0; c < 8; ++c)
#pragma unroll
      for (int r = 0; r < 4; ++r) oa[c][r] *= al[r];

    bf16_t* myP = Ps + wave * 16 * 40;
#pragma unroll
    for (int r = 0; r < 4; ++r) {
      myP[(lq * 4 + r) * 40 + ln]      = (bf16_t)p0[r];
      myP[(lq * 4 + r) * 40 + 16 + ln] = (bf16_t)p1[r];
    }
    __syncthreads();
    bf16x8_t pf = *(const bf16x8_t*)(myP + ln * 40 + lq * 8);
#pragma unroll
    for (int c = 0; c < 8; ++c) {
      bf16x8_t vf = *(const bf16x8_t*)(Vs + (c * 16 + ln) * 40 + lq * 8);
      oa[c] = __builtin_amdgcn_mfma_f32_16x16x32_bf16(pf, vf, oa[c], 0, 0, 0);
    }
  }

#pragma unroll
  for (int c = 0; c < 8; ++c)
#pragma unroll
    for (int r = 0; r < 4; ++r) {
      int row = q0 + wave * 16 + lq * 4 + r;
      O[(size_t)row * HID + head * HD + c * 16 + ln] =
          (bf16_t)(oa[c][r] / l_r[r]);
    }
}

// ---------------------------------------------------------------------------
extern "C" void kernel_launch(void* const* d_in, const int* in_sizes, int n_in,
                              void* d_out, int out_size, void* d_ws, size_t ws_size,
                              hipStream_t stream)
{
  (void)in_sizes; (void)n_in; (void)out_size; (void)d_ws; (void)ws_size;
  const float* hs = (const float*)d_in[0];
  // d_in[1] = attention_mask (pure causal -1e9) -> implemented analytically
  const float* wq = (const float*)d_in[2];
  const float* wk = (const float*)d_in[3];
  const float* wv = (const float*)d_in[4];
  const float* wo = (const float*)d_in[5];
  const float* cs = (const float*)d_in[6];
  const float* sn = (const float*)d_in[7];
  float* out = (float*)d_out;

  bf16_t *hsb, *wqT, *wkT, *wvT, *woT, *q, *k, *v, *vT, *ao;
  hipGetSymbolAddress((void**)&hsb, HIP_SYMBOL(g_hsb));
  hipGetSymbolAddress((void**)&wqT, HIP_SYMBOL(g_wqT));
  hipGetSymbolAddress((void**)&wkT, HIP_SYMBOL(g_wkT));
  hipGetSymbolAddress((void**)&wvT, HIP_SYMBOL(g_wvT));
  hipGetSymbolAddress((void**)&woT, HIP_SYMBOL(g_woT));
  hipGetSymbolAddress((void**)&q,   HIP_SYMBOL(g_q));
  hipGetSymbolAddress((void**)&k,   HIP_SYMBOL(g_k));
  hipGetSymbolAddress((void**)&v,   HIP_SYMBOL(g_v));
  hipGetSymbolAddress((void**)&vT,  HIP_SYMBOL(g_vT));
  hipGetSymbolAddress((void**)&ao,  HIP_SYMBOL(g_ao));

  // hidden_states fp32 -> bf16
  cast_f32_bf16<<<(S_LEN * HID) / (256 * 8), 256, 0, stream>>>(hs, hsb);

  // weight transposes (+cast): w[K][N] fp32 -> wT[N][K] bf16
  transpose_f32_bf16<<<dim3(64, 64), 256, 0, stream>>>(wq, wqT, HID, HID);
  transpose_f32_bf16<<<dim3(64, 16), 256, 0, stream>>>(wk, wkT, KV_DIM, HID);
  transpose_f32_bf16<<<dim3(64, 16), 256, 0, stream>>>(wv, wvT, KV_DIM, HID);
  transpose_f32_bf16<<<dim3(64, 64), 256, 0, stream>>>(wo, woT, HID, HID);

  // projections (bf16 out)
  gemm_bt<bf16_t><<<dim3(S_LEN / 64, HID / 64), 256, 0, stream>>>(hsb, wqT, q, HID, HID);
  gemm_bt<bf16_t><<<dim3(S_LEN / 64, KV_DIM / 64), 256, 0, stream>>>(hsb, wkT, k, HID, KV_DIM);
  gemm_bt<bf16_t><<<dim3(S_LEN / 64, KV_DIM / 64), 256, 0, stream>>>(hsb, wvT, v, HID, KV_DIM);

  // RoPE on q and k
  rope_kernel<<<(S_LEN * (NH + NKV) * 64) / 256, 256, 0, stream>>>(q, k, cs, sn);

  // v[s][kvh*128+d] -> vT[kvh][d][s]
  transpose_bf16<<<dim3(S_LEN / 64, HD / 64, NKV), 256, 0, stream>>>(
      v, vT, KV_DIM, S_LEN, HD, HD * S_LEN);

  // attention
  attn_kernel<<<dim3(S_LEN / 64, NH), 256, 0, stream>>>(q, k, vT, ao);

  // output projection (fp32 out)
  gemm_bt<float><<<dim3(S_LEN / 64, HID / 64), 256, 0, stream>>>(ao, woT, out, HID, HID);
}

// Round 3
// 673.632 us; speedup vs baseline: 1.5471x; 1.5471x over previous
//
#include <hip/hip_runtime.h>

// ---------------------------------------------------------------------------
// LlamaAttention fwd: B=1, S=2048, HID=4096, NH=32, NKV=8, HD=128, GQA x4.
// fp32 in/out; bf16 MFMA internally. R3: m97-style 128x128 GEMM w/
// global_load_lds, fused QKV GEMM (N=6144), BK=64 flash attention with
// longest-first dispatch.
// ---------------------------------------------------------------------------

typedef __bf16 bf16_t;
typedef bf16_t bf16x8_t __attribute__((ext_vector_type(8)));
typedef float f32x4_t __attribute__((ext_vector_type(4)));

#define S_LEN 2048
#define HID 4096
#define NH 32
#define NKV 8
#define HD 128
#define KV_DIM 1024
#define QKV_DIM 6144                 // 4096 q | 1024 k | 1024 v
#define SCALE 0.08838834764831845f   // 1/sqrt(128)

// -------- persistent device scratch ----------------------------------------
__device__ __align__(16) bf16_t g_hsb[(size_t)S_LEN * HID];
__device__ __align__(16) bf16_t g_wqkvT[(size_t)QKV_DIM * HID];  // [n][k]
__device__ __align__(16) bf16_t g_woT[(size_t)HID * HID];        // [n][k]
__device__ __align__(16) bf16_t g_qkv[(size_t)S_LEN * QKV_DIM];  // post-RoPE
__device__ __align__(16) bf16_t g_vT[(size_t)NKV * HD * S_LEN];  // [kvh][d][s]
__device__ __align__(16) bf16_t g_ao[(size_t)S_LEN * HID];       // attn out

// async global->LDS, 16B per lane; LDS dest is wave-uniform base + lane*16
__device__ __forceinline__ void gl_lds16(const bf16_t* g, bf16_t* l) {
  __builtin_amdgcn_global_load_lds(
      (const __attribute__((address_space(1))) void*)g,
      (__attribute__((address_space(3))) void*)l, 16, 0, 0);
}

// ---------------------------------------------------------------------------
__global__ __launch_bounds__(256) void cast_f32_bf16(
    const float* __restrict__ in, bf16_t* __restrict__ out)
{
  size_t i = ((size_t)blockIdx.x * 256 + threadIdx.x) * 8;
  float4 a = *(const float4*)(in + i);
  float4 b = *(const float4*)(in + i + 4);
  bf16x8_t r;
  r[0] = (bf16_t)a.x; r[1] = (bf16_t)a.y; r[2] = (bf16_t)a.z; r[3] = (bf16_t)a.w;
  r[4] = (bf16_t)b.x; r[5] = (bf16_t)b.y; r[6] = (bf16_t)b.z; r[7] = (bf16_t)b.w;
  *(bf16x8_t*)(out + i) = r;
}

// ---------------------------------------------------------------------------
// Transpose+cast: in fp32 [R][C] stride is -> out bf16 [C][R] stride os.
// ---------------------------------------------------------------------------
__global__ __launch_bounds__(256) void transpose_f32_bf16(
    const float* __restrict__ in, bf16_t* __restrict__ out, int is, int os)
{
  __shared__ __align__(16) bf16_t T[64 * 72];
  int r0 = blockIdx.x * 64, c0 = blockIdx.y * 64;
  int t = threadIdx.x;
#pragma unroll
  for (int it = 0; it < 2; ++it) {
    int idx = t + it * 256;
    int r = idx >> 3, c8 = (idx & 7) * 8;
    const float* p = in + (size_t)(r0 + r) * is + c0 + c8;
    float4 a = *(const float4*)p;
    float4 b = *(const float4*)(p + 4);
    bf16x8_t x;
    x[0] = (bf16_t)a.x; x[1] = (bf16_t)a.y; x[2] = (bf16_t)a.z; x[3] = (bf16_t)a.w;
    x[4] = (bf16_t)b.x; x[5] = (bf16_t)b.y; x[6] = (bf16_t)b.z; x[7] = (bf16_t)b.w;
    *(bf16x8_t*)(T + r * 72 + c8) = x;
  }
  __syncthreads();
#pragma unroll
  for (int it = 0; it < 2; ++it) {
    int idx = t + it * 256;
    int c = idx >> 3, r8 = (idx & 7) * 8;
    bf16x8_t x;
#pragma unroll
    for (int i = 0; i < 8; ++i) x[i] = T[(r8 + i) * 72 + c];
    *(bf16x8_t*)(out + (size_t)(c0 + c) * os + r0 + r8) = x;
  }
}

// ---------------------------------------------------------------------------
// bf16 batched transpose (V -> V^T per kv head).
// ---------------------------------------------------------------------------
__global__ __launch_bounds__(256) void transpose_bf16(
    const bf16_t* __restrict__ in, bf16_t* __restrict__ out,
    int is, int os, int in_b, int out_b)
{
  __shared__ __align__(16) bf16_t T[64 * 72];
  const bf16_t* inp = in + (size_t)blockIdx.z * in_b;
  bf16_t* outp = out + (size_t)blockIdx.z * out_b;
  int r0 = blockIdx.x * 64, c0 = blockIdx.y * 64;
  int t = threadIdx.x;
#pragma unroll
  for (int it = 0; it < 2; ++it) {
    int idx = t + it * 256;
    int r = idx >> 3, c8 = (idx & 7) * 8;
    *(bf16x8_t*)(T + r * 72 + c8) =
        *(const bf16x8_t*)(inp + (size_t)(r0 + r) * is + c0 + c8);
  }
  __syncthreads();
#pragma unroll
  for (int it = 0; it < 2; ++it) {
    int idx = t + it * 256;
    int c = idx >> 3, r8 = (idx & 7) * 8;
    bf16x8_t x;
#pragma unroll
    for (int i = 0; i < 8; ++i) x[i] = T[(r8 + i) * 72 + c];
    *(bf16x8_t*)(outp + (size_t)(c0 + c) * os + r0 + r8) = x;
  }
}

// ---------------------------------------------------------------------------
// m97-style GEMM: C[M,N] = A[M,K] @ Bt[N,K]^T. 128x128 tile, BK=32, 4 waves,
// each wave one 64x64 quadrant (4x4 MFMA tiles). global_load_lds staging
// (LDS layout contiguous in lane order, NO padding).
// ---------------------------------------------------------------------------
template <typename CT>
__global__ __launch_bounds__(256) void gemm128(
    const bf16_t* __restrict__ A, const bf16_t* __restrict__ Bt,
    CT* __restrict__ C, int K, int N)
{
  __shared__ __align__(16) bf16_t As[128 * 32];   // [m][k]
  __shared__ __align__(16) bf16_t Bs[128 * 32];   // [n][k]
  int t = threadIdx.x;
  int wave = t >> 6, lane = t & 63, ln = lane & 15, lq = lane >> 4;
  int m0 = blockIdx.x * 128, n0 = blockIdx.y * 128;
  int wm = (wave >> 1) * 64, wn = (wave & 1) * 64;
  // staging: wave stages 16 rows per issue (64 lanes x 16B = 16 rows of 32)
  int srow = wave * 16 + (lane >> 2);
  int skc = (lane & 3) * 8;
  const bf16_t* Ag0 = A + (size_t)(m0 + srow) * K + skc;
  const bf16_t* Ag1 = A + (size_t)(m0 + 64 + srow) * K + skc;
  const bf16_t* Bg0 = Bt + (size_t)(n0 + srow) * K + skc;
  const bf16_t* Bg1 = Bt + (size_t)(n0 + 64 + srow) * K + skc;
  bf16_t* Al0 = As + (wave * 16) * 32;      // wave-uniform LDS bases
  bf16_t* Al1 = As + (64 + wave * 16) * 32;
  bf16_t* Bl0 = Bs + (wave * 16) * 32;
  bf16_t* Bl1 = Bs + (64 + wave * 16) * 32;
  f32x4_t acc[4][4] = {};
  for (int k0 = 0; k0 < K; k0 += 32) {
    __syncthreads();
    gl_lds16(Ag0 + k0, Al0);
    gl_lds16(Ag1 + k0, Al1);
    gl_lds16(Bg0 + k0, Bl0);
    gl_lds16(Bg1 + k0, Bl1);
    __syncthreads();
    bf16x8_t af[4], bfr[4];
#pragma unroll
    for (int i = 0; i < 4; ++i) {
      af[i]  = *(const bf16x8_t*)(As + (wm + i * 16 + ln) * 32 + lq * 8);
      bfr[i] = *(const bf16x8_t*)(Bs + (wn + i * 16 + ln) * 32 + lq * 8);
    }
#pragma unroll
    for (int mt = 0; mt < 4; ++mt)
#pragma unroll
      for (int nt = 0; nt < 4; ++nt)
        acc[mt][nt] = __builtin_amdgcn_mfma_f32_16x16x32_bf16(
            af[mt], bfr[nt], acc[mt][nt], 0, 0, 0);
  }
#pragma unroll
  for (int mt = 0; mt < 4; ++mt)
#pragma unroll
    for (int nt = 0; nt < 4; ++nt)
#pragma unroll
      for (int r = 0; r < 4; ++r)
        C[(size_t)(m0 + wm + mt * 16 + lq * 4 + r) * N + n0 + wn + nt * 16 + ln] =
            (CT)acc[mt][nt][r];
}

// ---------------------------------------------------------------------------
// RoPE in-place on fused qkv layout [s][6144]; cos/sin fp32 [S][128].
// ---------------------------------------------------------------------------
__global__ __launch_bounds__(256) void rope_kernel(
    bf16_t* __restrict__ qkv, const float* __restrict__ cs,
    const float* __restrict__ sn)
{
  int idx = blockIdx.x * 256 + threadIdx.x;   // S*(NH+NKV)*64 threads exact
  int d = idx & 63;
  int h = (idx >> 6) % (NH + NKV);
  int s = idx / (64 * (NH + NKV));
  float c = cs[s * HD + d], si = sn[s * HD + d];
  bf16_t* base = qkv + (size_t)s * QKV_DIM +
                 ((h < NH) ? h * HD : HID + (h - NH) * HD);
  float x1 = (float)base[d], x2 = (float)base[d + 64];
  base[d]      = (bf16_t)(x1 * c - x2 * si);
  base[d + 64] = (bf16_t)(x2 * c + x1 * si);
}

// ---------------------------------------------------------------------------
// Flash attention, causal, GQA. BK=64 k-tile, 64 q-rows/block (16/wave).
// Longest-first dispatch: qb = 31 - bid/32, head = bid%32.
// 32 MFMA per barrier pair; per-wave P slice needs no barrier.
// ---------------------------------------------------------------------------
__global__ __launch_bounds__(256) void attn_kernel(
    const bf16_t* __restrict__ QKV, const bf16_t* __restrict__ VT,
    bf16_t* __restrict__ O)
{
  __shared__ __align__(16) bf16_t Ks[64 * 136];    // [kpos][d], pad 128->136
  __shared__ __align__(16) bf16_t Vs[128 * 72];    // [d][kpos], pad 64->72
  __shared__ __align__(16) bf16_t Ps[4 * 16 * 72]; // per-wave [16 q][64 k]
  int t = threadIdx.x, wave = t >> 6, lane = t & 63;
  int ln = lane & 15, lq = lane >> 4;
  int bid = blockIdx.x;
  int qb = (S_LEN / 64 - 1) - (bid >> 5);
  int head = bid & 31, kvh = head >> 2;
  int q0 = qb * 64;
  int qr = q0 + wave * 16 + ln;

  bf16x8_t qf[4];
#pragma unroll
  for (int kk = 0; kk < 4; ++kk)
    qf[kk] = *(const bf16x8_t*)(QKV + (size_t)qr * QKV_DIM + head * HD +
                                kk * 32 + lq * 8);

  f32x4_t oa[8] = {};
  float m_r[4] = {-1e30f, -1e30f, -1e30f, -1e30f};
  float l_r[4] = {0.f, 0.f, 0.f, 0.f};

  int krow = t >> 4, kdc = (t & 15) * 8;   // Ks staging: 16 rows/pass
  int vrow = t >> 3, vkc = (t & 7) * 8;    // Vs staging: 32 rows/pass
  const bf16_t* Kg = QKV + HID + (size_t)kvh * HD;
  const bf16_t* Vg = VT + (size_t)kvh * HD * S_LEN;

  for (int kt = 0; kt <= qb; ++kt) {
    int kb = kt * 64;
    __syncthreads();
#pragma unroll
    for (int p = 0; p < 4; ++p) {
      int r_ = p * 16 + krow;
      *(bf16x8_t*)(Ks + r_ * 136 + kdc) =
          *(const bf16x8_t*)(Kg + (size_t)(kb + r_) * QKV_DIM + kdc);
      int d_ = p * 32 + vrow;
      *(bf16x8_t*)(Vs + d_ * 72 + vkc) =
          *(const bf16x8_t*)(Vg + (size_t)d_ * S_LEN + kb + vkc);
    }
    __syncthreads();

    // S = Q @ K^T : 4 col-tiles x 4 k-chunks
    f32x4_t sv[4] = {};
#pragma unroll
    for (int nt = 0; nt < 4; ++nt)
#pragma unroll
      for (int kk = 0; kk < 4; ++kk) {
        bf16x8_t kf = *(const bf16x8_t*)(Ks + (nt * 16 + ln) * 136 +
                                         kk * 32 + lq * 8);
        sv[nt] = __builtin_amdgcn_mfma_f32_16x16x32_bf16(qf[kk], kf, sv[nt],
                                                         0, 0, 0);
      }

    float p_[4][4];                        // [nt][r]
    if (kt == qb) {                        // diagonal tile: mask (uniform br.)
#pragma unroll
      for (int nt = 0; nt < 4; ++nt)
#pragma unroll
        for (int r = 0; r < 4; ++r) {
          int rq = wave * 16 + lq * 4 + r;
          p_[nt][r] = (nt * 16 + ln <= rq) ? sv[nt][r] * SCALE : -1e30f;
        }
    } else {
#pragma unroll
      for (int nt = 0; nt < 4; ++nt)
#pragma unroll
        for (int r = 0; r < 4; ++r) p_[nt][r] = sv[nt][r] * SCALE;
    }

    float mx[4];
#pragma unroll
    for (int r = 0; r < 4; ++r)
      mx[r] = fmaxf(fmaxf(p_[0][r], p_[1][r]), fmaxf(p_[2][r], p_[3][r]));
#pragma unroll
    for (int off = 8; off >= 1; off >>= 1)
#pragma unroll
      for (int r = 0; r < 4; ++r) mx[r] = fmaxf(mx[r], __shfl_xor(mx[r], off, 64));

    float al[4], rs[4];
#pragma unroll
    for (int r = 0; r < 4; ++r) {
      float mn = fmaxf(m_r[r], mx[r]);
      al[r] = __expf(m_r[r] - mn);
      m_r[r] = mn;
      rs[r] = 0.f;
#pragma unroll
      for (int nt = 0; nt < 4; ++nt) {
        p_[nt][r] = __expf(p_[nt][r] - mn);
        rs[r] += p_[nt][r];
      }
    }
#pragma unroll
    for (int off = 8; off >= 1; off >>= 1)
#pragma unroll
      for (int r = 0; r < 4; ++r) rs[r] += __shfl_xor(rs[r], off, 64);
#pragma unroll
    for (int r = 0; r < 4; ++r) l_r[r] = l_r[r] * al[r] + rs[r];
#pragma unroll
    for (int dt = 0; dt < 8; ++dt)
#pragma unroll
      for (int r = 0; r < 4; ++r) oa[dt][r] *= al[r];

    // P: C/D layout -> per-wave LDS slice -> A-operand layout (no barrier)
    bf16_t* myP = Ps + wave * 16 * 72;
#pragma unroll
    for (int nt = 0; nt < 4; ++nt)
#pragma unroll
      for (int r = 0; r < 4; ++r)
        myP[(lq * 4 + r) * 72 + nt * 16 + ln] = (bf16_t)p_[nt][r];
    bf16x8_t pf0 = *(const bf16x8_t*)(myP + ln * 72 + lq * 8);
    bf16x8_t pf1 = *(const bf16x8_t*)(myP + ln * 72 + 32 + lq * 8);
#pragma unroll
    for (int dt = 0; dt < 8; ++dt) {
      bf16x8_t v0 = *(const bf16x8_t*)(Vs + (dt * 16 + ln) * 72 + lq * 8);
      bf16x8_t v1 = *(const bf16x8_t*)(Vs + (dt * 16 + ln) * 72 + 32 + lq * 8);
      oa[dt] = __builtin_amdgcn_mfma_f32_16x16x32_bf16(pf0, v0, oa[dt], 0, 0, 0);
      oa[dt] = __builtin_amdgcn_mfma_f32_16x16x32_bf16(pf1, v1, oa[dt], 0, 0, 0);
    }
  }

#pragma unroll
  for (int dt = 0; dt < 8; ++dt)
#pragma unroll
    for (int r = 0; r < 4; ++r) {
      int row = q0 + wave * 16 + lq * 4 + r;
      O[(size_t)row * HID + head * HD + dt * 16 + ln] =
          (bf16_t)(oa[dt][r] / l_r[r]);
    }
}

// ---------------------------------------------------------------------------
extern "C" void kernel_launch(void* const* d_in, const int* in_sizes, int n_in,
                              void* d_out, int out_size, void* d_ws, size_t ws_size,
                              hipStream_t stream)
{
  (void)in_sizes; (void)n_in; (void)out_size; (void)d_ws; (void)ws_size;
  const float* hs = (const float*)d_in[0];
  // d_in[1] = attention_mask (pure causal) -> analytic
  const float* wq = (const float*)d_in[2];
  const float* wk = (const float*)d_in[3];
  const float* wv = (const float*)d_in[4];
  const float* wo = (const float*)d_in[5];
  const float* cs = (const float*)d_in[6];
  const float* sn = (const float*)d_in[7];
  float* out = (float*)d_out;

  bf16_t *hsb, *wqkvT, *woT, *qkv, *vT, *ao;
  hipGetSymbolAddress((void**)&hsb,   HIP_SYMBOL(g_hsb));
  hipGetSymbolAddress((void**)&wqkvT, HIP_SYMBOL(g_wqkvT));
  hipGetSymbolAddress((void**)&woT,   HIP_SYMBOL(g_woT));
  hipGetSymbolAddress((void**)&qkv,   HIP_SYMBOL(g_qkv));
  hipGetSymbolAddress((void**)&vT,    HIP_SYMBOL(g_vT));
  hipGetSymbolAddress((void**)&ao,    HIP_SYMBOL(g_ao));

  // hidden_states fp32 -> bf16
  cast_f32_bf16<<<(S_LEN * HID) / (256 * 8), 256, 0, stream>>>(hs, hsb);

  // weight transposes (+cast) into fused wqkvT rows [0,4096,5120] and woT
  transpose_f32_bf16<<<dim3(64, 64), 256, 0, stream>>>(wq, wqkvT, HID, HID);
  transpose_f32_bf16<<<dim3(64, 16), 256, 0, stream>>>(
      wk, wqkvT + (size_t)HID * HID, KV_DIM, HID);
  transpose_f32_bf16<<<dim3(64, 16), 256, 0, stream>>>(
      wv, wqkvT + (size_t)(HID + KV_DIM) * HID, KV_DIM, HID);
  transpose_f32_bf16<<<dim3(64, 64), 256, 0, stream>>>(wo, woT, HID, HID);

  // fused QKV projection: [2048,4096] @ [6144,4096]^T -> [2048,6144]
  gemm128<bf16_t><<<dim3(S_LEN / 128, QKV_DIM / 128), 256, 0, stream>>>(
      hsb, wqkvT, qkv, HID, QKV_DIM);

  // RoPE on q and k (in fused layout)
  rope_kernel<<<(S_LEN * (NH + NKV) * 64) / 256, 256, 0, stream>>>(qkv, cs, sn);

  // v section [s][kvh*128+d] -> vT[kvh][d][s]
  transpose_bf16<<<dim3(S_LEN / 64, HD / 64, NKV), 256, 0, stream>>>(
      qkv + HID + KV_DIM, vT, QKV_DIM, S_LEN, HD, HD * S_LEN);

  // attention (longest blocks first)
  attn_kernel<<<dim3((S_LEN / 64) * NH), 256, 0, stream>>>(qkv, vT, ao);

  // output projection (fp32 out)
  gemm128<float><<<dim3(S_LEN / 128, HID / 128), 256, 0, stream>>>(
      ao, woT, out, HID, HID);
}